// Round 12
// baseline (234.337 us; speedup 1.0000x reference)
//
#include <hip/hip_runtime.h>
#include <hip/hip_bf16.h>
#include <math.h>

#define LOG2E 1.4426950408889634f
#define IS6   0.4082482904638630f

typedef _Float16 h2 __attribute__((ext_vector_type(2)));

#if defined(__has_builtin)
#if __has_builtin(__builtin_amdgcn_fdot2)
#define FDOT2(a,b,c) __builtin_amdgcn_fdot2((a),(b),(c),false)
#endif
#if __has_builtin(__builtin_amdgcn_exp2f)
#define EXP2(x) __builtin_amdgcn_exp2f(x)
#endif
#endif
#ifndef FDOT2
#define FDOT2(a,b,c) ((float)(a).x*(float)(b).x + (float)(a).y*(float)(b).y + (c))
#endif
#ifndef EXP2
#define EXP2(x) exp2f(x)
#endif

__device__ __forceinline__ unsigned packh2(float x, float y) {
    h2 v; v.x = (_Float16)x; v.y = (_Float16)y;
    return *(unsigned*)&v;
}
__device__ __forceinline__ h2 ash2(unsigned u) { return *(h2*)&u; }
__device__ __forceinline__ unsigned ah2(h2 v) { return *(unsigned*)&v; }

#if defined(__has_builtin)
#if __has_builtin(__builtin_amdgcn_cvt_pkrtz)
__device__ __forceinline__ unsigned pk2u(float a, float b) {
    auto r = __builtin_amdgcn_cvt_pkrtz(a, b);
    union { decltype(r) f; unsigned u; } c; c.f = r; return c.u;
}
#define HAVE_PK2 1
#endif
#endif
#ifndef HAVE_PK2
__device__ __forceinline__ unsigned pk2u(float a, float b) { return packh2(a, b); }
#endif

// ---------------- kernel 0: pack W (f32 col-major) -> Whp[mat][col][dpair] f16x2 ----------------
__global__ __launch_bounds__(96)
void k_wpack(const float* __restrict__ Wq, const float* __restrict__ Wk,
             const float* __restrict__ Wv, unsigned* __restrict__ Whp) {
    int bid = blockIdx.x;                   // mat*96 + dp
    int mat = bid / 96, dp = bid - mat * 96;
    const float* W = mat == 0 ? Wq : (mat == 1 ? Wk : Wv);
    int c = threadIdx.x;                    // 0..95
    float w0 = W[(2 * dp) * 96 + c];
    float w1 = W[(2 * dp + 1) * 96 + c];
    Whp[(mat * 96 + c) * 96 + dp] = packh2(w0, w1);
}

// ---------------- kernel 1: QKV (transposed stores, SoA planes) + phi table ----------------
__global__ __launch_bounds__(256)
void k_pre(const float* __restrict__ x, const unsigned* __restrict__ Whp,
           const float* __restrict__ bk, const float* __restrict__ bv,
           const float* __restrict__ rwb, const float* __restrict__ rrb,
           const float* __restrict__ rk,
           unsigned* __restrict__ QWt, unsigned* __restrict__ QRt,
           unsigned* __restrict__ Kpl, unsigned* __restrict__ Vpl,
           unsigned short* __restrict__ phiB) {
    __shared__ unsigned xs[64 * 97];        // 64 rows x 96 f16-pairs, pad 97
    __shared__ float rrowS[4 * 192];
    int tid = threadIdx.x;
    if (blockIdx.x < 1152) {
        int rt = blockIdx.x / 18, qb = blockIdx.x - rt * 18;
        int row0 = rt * 64;
        for (int idx = tid; idx < 6144; idx += 256) {
            int r = idx / 96, dpp = idx - r * 96;
            float2 xv = *(const float2*)&x[(size_t)(row0 + r) * 192 + dpp * 2];
            xs[r * 97 + dpp] = packh2(xv.x, xv.y);
        }
        __syncthreads();
        int quad = __builtin_amdgcn_readfirstlane(tid >> 6);
        int sl = tid & 63;
        int cq = qb * 4 + quad;             // 0..71
        int c0 = cq * 4;                    // 0..284
        int mat = c0 / 96, col0 = c0 - mat * 96;
        const unsigned* wb0 = Whp + (mat * 96 + col0) * 96;
        const unsigned* wb1 = wb0 + 96;
        const unsigned* wb2 = wb0 + 192;
        const unsigned* wb3 = wb0 + 288;
        const unsigned* xr = xs + sl * 97;
        float a0 = 0.f, a1 = 0.f, a2 = 0.f, a3 = 0.f;
        #pragma unroll 8
        for (int dp = 0; dp < 96; ++dp) {
            h2 xp = ash2(xr[dp]);
            a0 = FDOT2(xp, ash2(wb0[dp]), a0);
            a1 = FDOT2(xp, ash2(wb1[dp]), a1);
            a2 = FDOT2(xp, ash2(wb2[dp]), a2);
            a3 = FDOT2(xp, ash2(wb3[dp]), a3);
        }
        float av[4] = {a0, a1, a2, a3};
        int row = row0 + sl, b = row >> 10, s = row & 1023;
        if (mat == 0) {
            #pragma unroll
            for (int pp = 0; pp < 2; ++pp) {
                int cA = col0 + 2 * pp;
                int pg = cA >> 1;
                int nn = pg / 3, hp = pg - nn * 3;
                int bnn = b * 16 + nn;
                unsigned qw = packh2((av[2*pp]   + rwb[cA])   * (IS6 * LOG2E),
                                     (av[2*pp+1] + rwb[cA+1]) * (IS6 * LOG2E));
                unsigned qr = packh2((av[2*pp]   + rrb[cA])   * (IS6 * LOG2E),
                                     (av[2*pp+1] + rrb[cA+1]) * (IS6 * LOG2E));
                size_t qo = ((size_t)(hp * 64 + bnn) << 10) + s;
                QWt[qo] = qw;
                QRt[qo] = qr;
            }
        } else if (mat == 1) {
            #pragma unroll
            for (int pp = 0; pp < 2; ++pp) {
                int cA = col0 + 2 * pp;
                int pg = cA >> 1;
                int nn = pg / 3, hp = pg - nn * 3;
                int bnn = b * 16 + nn;
                Kpl[((size_t)(hp * 64 + bnn) << 10) + s] =
                    packh2(av[2*pp] + bk[cA], av[2*pp+1] + bk[cA+1]);
            }
        } else {
            #pragma unroll
            for (int pp = 0; pp < 2; ++pp) {
                int cA = col0 + 2 * pp;
                int pg = cA >> 1;
                int nn = pg / 3, hp = pg - nn * 3;
                int bnn = b * 16 + nn;
                Vpl[((size_t)(hp * 64 + bnn) << 10) + s] =
                    packh2(av[2*pp] + bv[cA], av[2*pp+1] + bv[cA+1]);
            }
        }
    } else {
        // ---- phi: 4 t per block ----
        int t0 = (blockIdx.x - 1152) * 4;
        for (int idx = tid; idx < 768; idx += 256) {
            int tl = idx / 192, d = idx - tl * 192;
            int dd = d < 96 ? d : d - 96;
            float w = exp2f(-(float)dd * 0.13841367062030676f);  // log2(10000)/96
            float ang = (float)(1024 - (t0 + tl)) * w;
            rrowS[idx] = (d < 96) ? __sinf(ang) : __cosf(ang);
        }
        __syncthreads();
        if (tid < 192) {
            int c = tid % 96, tg = tid / 96;
            float acc0 = 0.f, acc1 = 0.f;
            #pragma unroll 4
            for (int d = 0; d < 192; ++d) {
                float wv = rk[d * 96 + c];
                acc0 += rrowS[(tg * 2 + 0) * 192 + d] * wv;
                acc1 += rrowS[(tg * 2 + 1) * 192 + d] * wv;
            }
            int n = c / 6, h = c - n * 6;
            _Float16 v0 = (_Float16)acc0, v1 = (_Float16)acc1;
            phiB[(n * 2048 + t0 + tg * 2 + 0) * 8 + h] = *(unsigned short*)&v0;
            phiB[(n * 2048 + t0 + tg * 2 + 1) * 8 + h] = *(unsigned short*)&v1;
            if (tg == 0 && c < 32) {
                int nn = c >> 1, hh = 6 + (c & 1);
                #pragma unroll
                for (int k = 0; k < 4; ++k)
                    phiB[(nn * 2048 + t0 + k) * 8 + hh] = 0;
            }
        }
    }
}

// ---------------- kernel 2: fused attention ----------------
// grid (32 jc, 16 n, 4 b) x 128 thr; thread = 8 ADJACENT queries i = 8*tid..8*tid+7.
// ALL array indices are compile-time literals (STEP/SCOREQ macros) so ph/qw/qr/ac
// stay in registers (rule #20: runtime-indexed ext_vector arrays go to scratch).
#define SWZ(r) ((r) ^ (((r) >> 3) & 7))
__global__ __launch_bounds__(128, 3)
void k_attn(const unsigned* __restrict__ QWt, const unsigned* __restrict__ QRt,
            const unsigned* __restrict__ Kpl, const unsigned* __restrict__ Vpl,
            const float* __restrict__ mask0,
            const unsigned short* __restrict__ phiB,
            uint4* __restrict__ P) {
    __shared__ uint4 phiS[1056];    // 16896 B, rows j0+1 .. j0+1055 of phiB[n]
    __shared__ uint4 kS[32];        // {k01,k23,k45, mterm_f32}
    __shared__ float vS[32][8];     // V rows pre-converted to f32 (pad to 32B)
    int tid = threadIdx.x;
    int jc = blockIdx.x, n = blockIdx.y, b = blockIdx.z;
    int j0 = jc * 32;
    int bn = b * 16 + n;

    const uint4* phg = (const uint4*)phiB + (n * 2048 + j0 + 1);
    for (int r = tid; r < 1055; r += 128) phiS[SWZ(r)] = phg[r];
    if (tid < 32) {
        int j = j0 + tid;
        size_t base = ((size_t)bn << 10) + j;
        float mt = 1e6f * (mask0[b * 1024 + j] - 1.0f) * LOG2E;
        kS[tid] = make_uint4(Kpl[base], Kpl[base + 65536], Kpl[base + 131072],
                             __float_as_uint(mt));
    } else if (tid < 64) {
        int r = tid - 32;
        int j = j0 + r;
        size_t base = ((size_t)bn << 10) + j;
        h2 va = ash2(Vpl[base]), vb = ash2(Vpl[base + 65536]), vc = ash2(Vpl[base + 131072]);
        vS[r][0] = (float)va.x; vS[r][1] = (float)va.y;
        vS[r][2] = (float)vb.x; vS[r][3] = (float)vb.y;
        vS[r][4] = (float)vc.x; vS[r][5] = (float)vc.y;
    }
    __syncthreads();

    int iA = tid * 8;
    h2 qw[8][3], qr[8][3];
    #pragma unroll
    for (int hp = 0; hp < 3; ++hp) {
        size_t off = (size_t)hp * 65536 + ((size_t)bn << 10) + iA;
        uint4 qa = *(const uint4*)&QWt[off];
        uint4 qb2 = *(const uint4*)&QWt[off + 4];
        qw[0][hp] = ash2(qa.x); qw[1][hp] = ash2(qa.y); qw[2][hp] = ash2(qa.z); qw[3][hp] = ash2(qa.w);
        qw[4][hp] = ash2(qb2.x); qw[5][hp] = ash2(qb2.y); qw[6][hp] = ash2(qb2.z); qw[7][hp] = ash2(qb2.w);
        uint4 ra = *(const uint4*)&QRt[off];
        uint4 rb = *(const uint4*)&QRt[off + 4];
        qr[0][hp] = ash2(ra.x); qr[1][hp] = ash2(ra.y); qr[2][hp] = ash2(ra.z); qr[3][hp] = ash2(ra.w);
        qr[4][hp] = ash2(rb.x); qr[5][hp] = ash2(rb.y); qr[6][hp] = ash2(rb.z); qr[7][hp] = ash2(rb.w);
    }

    float den[8] = {0.f,0.f,0.f,0.f,0.f,0.f,0.f,0.f};
    float ac[8][6] = {};
    int Cb = 1023 - iA;                 // local phi row for (q=0, jj=0)
    uint4 ph[8];
    ph[7] = phiS[SWZ(Cb - 1)];          // row for q=1 at jj=0: slot (0-1)&7 = 7
    ph[6] = phiS[SWZ(Cb - 2)];
    ph[5] = phiS[SWZ(Cb - 3)];
    ph[4] = phiS[SWZ(Cb - 4)];
    ph[3] = phiS[SWZ(Cb - 5)];
    ph[2] = phiS[SWZ(Cb - 6)];
    ph[1] = phiS[SWZ(Cb - 7)];

#define SCOREQ(qi, ki)                                                          \
    {                                                                           \
        uint4 p = ph[((ki) - (qi)) & 7];                                        \
        float sc = FDOT2(ash2(K.x), qw[qi][0],                                  \
                   FDOT2(ash2(K.y), qw[qi][1],                                  \
                   FDOT2(ash2(K.z), qw[qi][2], mt)));                           \
        sc = FDOT2(ash2(p.x), qr[qi][0],                                        \
             FDOT2(ash2(p.y), qr[qi][1],                                        \
             FDOT2(ash2(p.z), qr[qi][2], sc)));                                 \
        float e = EXP2(sc);                                                     \
        den[qi] += e;                                                           \
        ac[qi][0] += e * v0; ac[qi][1] += e * v1; ac[qi][2] += e * v2;          \
        ac[qi][3] += e * v3; ac[qi][4] += e * v4; ac[qi][5] += e * v5;          \
    }

#define STEP(ki)                                                                \
    {                                                                           \
        const int jj = j8 + (ki);                                               \
        ph[(ki) & 7] = phiS[SWZ(Cb + jj)];                                      \
        uint4 K = kS[jj];                                                       \
        float mt = __uint_as_float(K.w);                                        \
        float4 vq = *(const float4*)&vS[jj][0];                                 \
        float2 vq2 = *(const float2*)&vS[jj][4];                                \
        float v0 = vq.x, v1 = vq.y, v2 = vq.z, v3 = vq.w;                       \
        float v4 = vq2.x, v5 = vq2.y;                                           \
        SCOREQ(0, ki) SCOREQ(1, ki) SCOREQ(2, ki) SCOREQ(3, ki)                 \
        SCOREQ(4, ki) SCOREQ(5, ki) SCOREQ(6, ki) SCOREQ(7, ki)                 \
    }

    for (int j8 = 0; j8 < 32; j8 += 8) {
        STEP(0) STEP(1) STEP(2) STEP(3) STEP(4) STEP(5) STEP(6) STEP(7)
    }
#undef STEP
#undef SCOREQ

    size_t pb = ((size_t)(jc * 64 + bn)) << 10;   // chunk layout: [8 q][128 t]
    #pragma unroll
    for (int q = 0; q < 8; ++q) {
        uint4 st;
        st.x = __float_as_uint(den[q]);
        st.y = pk2u(ac[q][0], ac[q][1]);
        st.z = pk2u(ac[q][2], ac[q][3]);
        st.w = pk2u(ac[q][4], ac[q][5]);
        P[pb + q * 128 + tid] = st;
    }
}

// ---------------- kernel 3: combine 32 chunks (fully coalesced) -> AV[b][i][96] f32 ----------------
__global__ __launch_bounds__(256)
void k_comb(const uint4* __restrict__ P, float* __restrict__ AV) {
    int flat = blockIdx.x * 256 + threadIdx.x;   // bn*1024 + (q*128 + tt)
    int bn = flat >> 10, rem = flat & 1023;
    int q = rem >> 7, tt = rem & 127;
    int i = tt * 8 + q;                          // query index this slot holds
    int b = bn >> 4, n = bn & 15;
    float d = 0.f, s0 = 0.f, s1 = 0.f, s2 = 0.f, s3 = 0.f, s4 = 0.f, s5 = 0.f;
    #pragma unroll
    for (int jc = 0; jc < 32; ++jc) {
        uint4 u = P[(((size_t)(jc * 64 + bn)) << 10) + rem];   // lane-consecutive
        h2 x0 = ash2(u.y), x1 = ash2(u.z), x2 = ash2(u.w);
        d  += __uint_as_float(u.x);
        s0 += (float)x0.x; s1 += (float)x0.y;
        s2 += (float)x1.x; s3 += (float)x1.y;
        s4 += (float)x2.x; s5 += (float)x2.y;
    }
    float inv = 1.0f / d;
    float* o = AV + ((size_t)(b * 1024 + i)) * 96 + n * 6;
    o[0] = s0 * inv; o[1] = s1 * inv; o[2] = s2 * inv;
    o[3] = s3 * inv; o[4] = s4 * inv; o[5] = s5 * inv;
}

// ---------------- kernel 4: Wo projection + residual + LayerNorm ----------------
__global__ __launch_bounds__(256)
void k_out(const float* __restrict__ AV, const float* __restrict__ Wo,
           const float* __restrict__ bo, const float* __restrict__ x,
           const float* __restrict__ gamma, const float* __restrict__ beta,
           float* __restrict__ out) {
    __shared__ unsigned WoS[96 * 96];   // 36864 B
    __shared__ float avS[8 * 96];       // 3072 B
    int tid = threadIdx.x;
    int row0 = blockIdx.x * 8;
    for (int idx = tid; idx < 9216; idx += 256) {
        int c = idx / 96, pd = idx - c * 96;
        float2 w = *(const float2*)&Wo[c * 192 + pd * 2];
        WoS[idx] = packh2(w.x, w.y);
    }
    for (int idx = tid; idx < 768; idx += 256)
        avS[idx] = AV[(size_t)row0 * 96 + idx];
    __syncthreads();

    int lane = tid & 63, wv = tid >> 6;
    bool act = lane < 48;
    int d0 = lane * 4;
    #pragma unroll
    for (int rr = 0; rr < 2; ++rr) {
        int r = wv * 2 + rr, row = row0 + r;
        float ax = 0.f, ay = 0.f, az = 0.f, aw = 0.f;
        if (act) {
            float4 bq = *(const float4*)&bo[d0];
            float4 xq = *(const float4*)&x[(size_t)row * 192 + d0];
            ax = bq.x + xq.x; ay = bq.y + xq.y; az = bq.z + xq.z; aw = bq.w + xq.w;
            for (int c2 = 0; c2 < 96; ++c2) {
                float a = avS[r * 96 + c2];
                uint2 wp = *(uint2*)&WoS[c2 * 96 + lane * 2];
                h2 w0 = ash2(wp.x), w1 = ash2(wp.y);
                ax += a * (float)w0.x; ay += a * (float)w0.y;
                az += a * (float)w1.x; aw += a * (float)w1.y;
            }
        }
        float sum = act ? (ax + ay + az + aw) : 0.f;
        #pragma unroll
        for (int off = 32; off; off >>= 1) sum += __shfl_xor(sum, off, 64);
        float mu = sum * (1.0f / 192.0f);
        float dx = ax - mu, dy = ay - mu, dz = az - mu, dw = aw - mu;
        float vs = act ? (dx * dx + dy * dy + dz * dz + dw * dw) : 0.f;
        #pragma unroll
        for (int off = 32; off; off >>= 1) vs += __shfl_xor(vs, off, 64);
        float rstd = rsqrtf(vs * (1.0f / 192.0f) + 1e-9f);
        if (act) {
            float4 g = *(const float4*)&gamma[d0];
            float4 bb = *(const float4*)&beta[d0];
            float4 rv;
            rv.x = dx * rstd * g.x + bb.x;
            rv.y = dy * rstd * g.y + bb.y;
            rv.z = dz * rstd * g.z + bb.z;
            rv.w = dw * rstd * g.w + bb.w;
            *(float4*)&out[(size_t)row * 192 + d0] = rv;
        }
    }
}

// ---------------- launch ----------------
extern "C" void kernel_launch(void* const* d_in, const int* in_sizes, int n_in,
                              void* d_out, int out_size, void* d_ws, size_t ws_size,
                              hipStream_t stream) {
    const float* x        = (const float*)d_in[0];
    const float* mask0    = (const float*)d_in[1];
    const float* Wq       = (const float*)d_in[2];
    const float* Wk       = (const float*)d_in[3];
    const float* bk       = (const float*)d_in[4];
    const float* Wv       = (const float*)d_in[5];
    const float* bv       = (const float*)d_in[6];
    const float* Wo       = (const float*)d_in[7];
    const float* bo       = (const float*)d_in[8];
    const float* rwb      = (const float*)d_in[9];
    const float* rrb      = (const float*)d_in[10];
    const float* r_kernel = (const float*)d_in[11];
    const float* gamma    = (const float*)d_in[12];
    const float* beta     = (const float*)d_in[13];
    float* out = (float*)d_out;

    unsigned* QWt = (unsigned*)d_ws;                       // 196608 dwords
    unsigned* QRt = QWt + 196608;                          // 196608
    unsigned* Kpl = QRt + 196608;                          // 196608
    unsigned* Vpl = Kpl + 196608;                          // 196608
    uint4*    P   = (uint4*)(Vpl + 196608);                // 2097152 uint4 (32 MB)
    unsigned short* phiB = (unsigned short*)(P + 2097152); // 262144 ushorts
    unsigned* Whp = (unsigned*)(phiB + 262144);            // 27648 dwords
    float*    AV  = (float*)(Whp + 27648);                 // 393216 floats (1.5 MB)

    k_wpack<<<288, 96, 0, stream>>>(Wq, Wk, Wv, Whp);
    k_pre<<<1664, 256, 0, stream>>>(x, Whp, bk, bv, rwb, rrb, r_kernel,
                                    QWt, QRt, Kpl, Vpl, phiB);
    k_attn<<<dim3(32, 16, 4), 128, 0, stream>>>(QWt, QRt, Kpl, Vpl, mask0, phiB, P);
    k_comb<<<256, 256, 0, stream>>>(P, AV);
    k_out<<<512, 256, 0, stream>>>(AV, Wo, bo, x, gamma, beta, out);
}

// Round 13
// 91.247 us; speedup vs baseline: 2.5682x; 2.5682x over previous
//
#include <hip/hip_runtime.h>
#include <hip/hip_bf16.h>
#include <math.h>

#define LOG2E 1.4426950408889634f
#define IS6   0.4082482904638630f

typedef _Float16 h2 __attribute__((ext_vector_type(2)));

#if defined(__has_builtin)
#if __has_builtin(__builtin_amdgcn_fdot2)
#define FDOT2(a,b,c) __builtin_amdgcn_fdot2((a),(b),(c),false)
#endif
#if __has_builtin(__builtin_amdgcn_exp2f)
#define EXP2(x) __builtin_amdgcn_exp2f(x)
#endif
#endif
#ifndef FDOT2
#define FDOT2(a,b,c) ((float)(a).x*(float)(b).x + (float)(a).y*(float)(b).y + (c))
#endif
#ifndef EXP2
#define EXP2(x) exp2f(x)
#endif

__device__ __forceinline__ unsigned packh2(float x, float y) {
    h2 v; v.x = (_Float16)x; v.y = (_Float16)y;
    return *(unsigned*)&v;
}
__device__ __forceinline__ h2 ash2(unsigned u) { return *(h2*)&u; }
__device__ __forceinline__ unsigned ah2(h2 v) { return *(unsigned*)&v; }

#if defined(__has_builtin)
#if __has_builtin(__builtin_amdgcn_cvt_pkrtz)
__device__ __forceinline__ h2 pk2(float a, float b) {
    auto r = __builtin_amdgcn_cvt_pkrtz(a, b);   // __fp16 ext_vector(2)
    union { decltype(r) f; h2 h; } c; c.f = r; return c.h;
}
#define HAVE_PK2 1
#endif
#endif
#ifndef HAVE_PK2
__device__ __forceinline__ h2 pk2(float a, float b) {
    h2 v; v.x = (_Float16)a; v.y = (_Float16)b; return v;
}
#endif

// ---------------- kernel 0: pack W (f32 col-major) -> Whp[mat][col][dpair] f16x2 ----------------
__global__ __launch_bounds__(96)
void k_wpack(const float* __restrict__ Wq, const float* __restrict__ Wk,
             const float* __restrict__ Wv, unsigned* __restrict__ Whp) {
    int bid = blockIdx.x;                   // mat*96 + dp
    int mat = bid / 96, dp = bid - mat * 96;
    const float* W = mat == 0 ? Wq : (mat == 1 ? Wk : Wv);
    int c = threadIdx.x;                    // 0..95
    float w0 = W[(2 * dp) * 96 + c];
    float w1 = W[(2 * dp + 1) * 96 + c];
    Whp[(mat * 96 + c) * 96 + dp] = packh2(w0, w1);
}

// ---------------- kernel 1: QKV (transposed stores, SoA planes) + phi table ----------------
__global__ __launch_bounds__(256)
void k_pre(const float* __restrict__ x, const unsigned* __restrict__ Whp,
           const float* __restrict__ bk, const float* __restrict__ bv,
           const float* __restrict__ rwb, const float* __restrict__ rrb,
           const float* __restrict__ rk,
           unsigned* __restrict__ QWt, unsigned* __restrict__ QRt,
           unsigned* __restrict__ Kpl, unsigned* __restrict__ Vpl,
           unsigned short* __restrict__ phiB) {
    __shared__ unsigned xs[64 * 97];        // 64 rows x 96 f16-pairs, pad 97
    __shared__ float rrowS[4 * 192];
    int tid = threadIdx.x;
    if (blockIdx.x < 1152) {
        int rt = blockIdx.x / 18, qb = blockIdx.x - rt * 18;
        int row0 = rt * 64;
        for (int idx = tid; idx < 6144; idx += 256) {
            int r = idx / 96, dpp = idx - r * 96;
            float2 xv = *(const float2*)&x[(size_t)(row0 + r) * 192 + dpp * 2];
            xs[r * 97 + dpp] = packh2(xv.x, xv.y);
        }
        __syncthreads();
        int quad = __builtin_amdgcn_readfirstlane(tid >> 6);
        int sl = tid & 63;
        int cq = qb * 4 + quad;             // 0..71
        int c0 = cq * 4;                    // 0..284
        int mat = c0 / 96, col0 = c0 - mat * 96;
        const unsigned* wb0 = Whp + (mat * 96 + col0) * 96;
        const unsigned* wb1 = wb0 + 96;
        const unsigned* wb2 = wb0 + 192;
        const unsigned* wb3 = wb0 + 288;
        const unsigned* xr = xs + sl * 97;
        float a0 = 0.f, a1 = 0.f, a2 = 0.f, a3 = 0.f;
        #pragma unroll 8
        for (int dp = 0; dp < 96; ++dp) {
            h2 xp = ash2(xr[dp]);
            a0 = FDOT2(xp, ash2(wb0[dp]), a0);
            a1 = FDOT2(xp, ash2(wb1[dp]), a1);
            a2 = FDOT2(xp, ash2(wb2[dp]), a2);
            a3 = FDOT2(xp, ash2(wb3[dp]), a3);
        }
        float av[4] = {a0, a1, a2, a3};
        int row = row0 + sl, b = row >> 10, s = row & 1023;
        if (mat == 0) {
            #pragma unroll
            for (int pp = 0; pp < 2; ++pp) {
                int cA = col0 + 2 * pp;
                int pg = cA >> 1;
                int nn = pg / 3, hp = pg - nn * 3;
                int bnn = b * 16 + nn;
                unsigned qw = packh2((av[2*pp]   + rwb[cA])   * (IS6 * LOG2E),
                                     (av[2*pp+1] + rwb[cA+1]) * (IS6 * LOG2E));
                unsigned qr = packh2((av[2*pp]   + rrb[cA])   * (IS6 * LOG2E),
                                     (av[2*pp+1] + rrb[cA+1]) * (IS6 * LOG2E));
                size_t qo = ((size_t)(hp * 64 + bnn) << 10) + s;
                QWt[qo] = qw;
                QRt[qo] = qr;
            }
        } else if (mat == 1) {
            #pragma unroll
            for (int pp = 0; pp < 2; ++pp) {
                int cA = col0 + 2 * pp;
                int pg = cA >> 1;
                int nn = pg / 3, hp = pg - nn * 3;
                int bnn = b * 16 + nn;
                Kpl[((size_t)(hp * 64 + bnn) << 10) + s] =
                    packh2(av[2*pp] + bk[cA], av[2*pp+1] + bk[cA+1]);
            }
        } else {
            #pragma unroll
            for (int pp = 0; pp < 2; ++pp) {
                int cA = col0 + 2 * pp;
                int pg = cA >> 1;
                int nn = pg / 3, hp = pg - nn * 3;
                int bnn = b * 16 + nn;
                Vpl[((size_t)(hp * 64 + bnn) << 10) + s] =
                    packh2(av[2*pp] + bv[cA], av[2*pp+1] + bv[cA+1]);
            }
        }
    } else {
        // ---- phi: 4 t per block ----
        int t0 = (blockIdx.x - 1152) * 4;
        for (int idx = tid; idx < 768; idx += 256) {
            int tl = idx / 192, d = idx - tl * 192;
            int dd = d < 96 ? d : d - 96;
            float w = exp2f(-(float)dd * 0.13841367062030676f);  // log2(10000)/96
            float ang = (float)(1024 - (t0 + tl)) * w;
            rrowS[idx] = (d < 96) ? __sinf(ang) : __cosf(ang);
        }
        __syncthreads();
        if (tid < 192) {
            int c = tid % 96, tg = tid / 96;
            float acc0 = 0.f, acc1 = 0.f;
            #pragma unroll 4
            for (int d = 0; d < 192; ++d) {
                float wv = rk[d * 96 + c];
                acc0 += rrowS[(tg * 2 + 0) * 192 + d] * wv;
                acc1 += rrowS[(tg * 2 + 1) * 192 + d] * wv;
            }
            int n = c / 6, h = c - n * 6;
            _Float16 v0 = (_Float16)acc0, v1 = (_Float16)acc1;
            phiB[(n * 2048 + t0 + tg * 2 + 0) * 8 + h] = *(unsigned short*)&v0;
            phiB[(n * 2048 + t0 + tg * 2 + 1) * 8 + h] = *(unsigned short*)&v1;
            if (tg == 0 && c < 32) {
                int nn = c >> 1, hh = 6 + (c & 1);
                #pragma unroll
                for (int k = 0; k < 4; ++k)
                    phiB[(nn * 2048 + t0 + k) * 8 + hh] = 0;
            }
        }
    }
}

// ---------------- kernel 2: fused attention ----------------
// grid (16 jc, 16 n, 4 b) x 256 thr; thread = 4 ADJACENT queries i = 4*tid .. 4*tid+3.
// 64 j per block. phi register chain: one ds_read_b128 per iter serves all 4 queries.
#define SWZ(r) ((r) ^ (((r) >> 3) & 7))
__global__ __launch_bounds__(256, 6)
void k_attn(const unsigned* __restrict__ QWt, const unsigned* __restrict__ QRt,
            const unsigned* __restrict__ Kpl, const unsigned* __restrict__ Vpl,
            const float* __restrict__ mask0,
            const unsigned short* __restrict__ phiB,
            uint4* __restrict__ P) {
    __shared__ uint4 phiS[1088];    // 17408 B: local rows 0..1087 = phiB rows j0+1 ..
    __shared__ uint4 kS[64];        // {k01,k23,k45, mterm_f32}
    __shared__ unsigned vS[192];    // 64 rows x 3 dwords {v01,v23,v45}
    int tid = threadIdx.x;
    int jc = blockIdx.x, n = blockIdx.y, b = blockIdx.z;
    int j0 = jc * 64;
    int bn = b * 16 + n;

    const uint4* phg = (const uint4*)phiB + (n * 2048 + j0 + 1);
    for (int r = tid; r < 1088; r += 256) phiS[SWZ(r)] = phg[r];
    if (tid < 64) {
        int j = j0 + tid;
        size_t base = ((size_t)bn << 10) + j;
        float mt = 1e6f * (mask0[b * 1024 + j] - 1.0f) * LOG2E;
        kS[tid] = make_uint4(Kpl[base], Kpl[base + 65536], Kpl[base + 131072],
                             __float_as_uint(mt));
    } else if (tid < 128) {
        int r = tid - 64;
        int j = j0 + r;
        size_t base = ((size_t)bn << 10) + j;
        vS[r * 3 + 0] = Vpl[base];
        vS[r * 3 + 1] = Vpl[base + 65536];
        vS[r * 3 + 2] = Vpl[base + 131072];
    }
    __syncthreads();

    int iA = tid * 4;
    h2 qw[4][3], qr[4][3];
    #pragma unroll
    for (int hp = 0; hp < 3; ++hp) {
        size_t off = (size_t)hp * 65536 + ((size_t)bn << 10) + iA;
        uint4 qa = *(const uint4*)&QWt[off];
        qw[0][hp] = ash2(qa.x); qw[1][hp] = ash2(qa.y);
        qw[2][hp] = ash2(qa.z); qw[3][hp] = ash2(qa.w);
        uint4 ra = *(const uint4*)&QRt[off];
        qr[0][hp] = ash2(ra.x); qr[1][hp] = ash2(ra.y);
        qr[2][hp] = ash2(ra.z); qr[3][hp] = ash2(ra.w);
    }

    float den[4] = {0.f, 0.f, 0.f, 0.f};
    h2 zero2; zero2.x = (_Float16)0.f; zero2.y = (_Float16)0.f;
    h2 ac0[4], ac1[4], ac2[4];
    #pragma unroll
    for (int q = 0; q < 4; ++q) { ac0[q] = zero2; ac1[q] = zero2; ac2[q] = zero2; }

    int Cb = 1023 - iA;                 // local phi row for (q=0, jj=0)
    uint4 ph[4];
    ph[3] = phiS[SWZ(Cb - 1)];          // (jj=0, q=1) -> (0-1)&3 = 3
    ph[2] = phiS[SWZ(Cb - 2)];          // q=2
    ph[1] = phiS[SWZ(Cb - 3)];          // q=3
    uint4 nxt = phiS[SWZ(Cb)];          // prefetch row for jj=0

    #pragma unroll 4
    for (int jj = 0; jj < 64; ++jj) {
        uint4 K = kS[jj];
        unsigned Vx = vS[3 * jj], Vy = vS[3 * jj + 1], Vz = vS[3 * jj + 2];
        ph[jj & 3] = nxt;
        nxt = phiS[SWZ(Cb + jj + 1)];   // lookahead; last iter reads <= 1087, in-bounds
        float mt = __uint_as_float(K.w);
        h2 v01 = ash2(Vx), v23 = ash2(Vy), v45 = ash2(Vz);
        #pragma unroll
        for (int q = 0; q < 4; ++q) {
            uint4 p = ph[(jj - q) & 3];
            float sc = FDOT2(ash2(K.x), qw[q][0],
                       FDOT2(ash2(K.y), qw[q][1],
                       FDOT2(ash2(K.z), qw[q][2], mt)));
            sc = FDOT2(ash2(p.x), qr[q][0],
                 FDOT2(ash2(p.y), qr[q][1],
                 FDOT2(ash2(p.z), qr[q][2], sc)));
            float e = EXP2(sc);
            den[q] += e;
            h2 e2 = pk2(e, e);
            ac0[q] += e2 * v01;
            ac1[q] += e2 * v23;
            ac2[q] += e2 * v45;
        }
    }
    size_t pb = ((size_t)(jc * 64 + bn)) << 10;   // chunk layout: [4 q][256 tt]
    #pragma unroll
    for (int q = 0; q < 4; ++q) {
        uint4 st;
        st.x = __float_as_uint(den[q]);
        st.y = ah2(ac0[q]); st.z = ah2(ac1[q]); st.w = ah2(ac2[q]);
        P[pb + q * 256 + tid] = st;
    }
}

// ---------------- kernel 3: combine 16 chunks (fully coalesced) -> AV[b][i][96] f32 ----------------
__global__ __launch_bounds__(256)
void k_comb(const uint4* __restrict__ P, float* __restrict__ AV) {
    int flat = blockIdx.x * 256 + threadIdx.x;   // bn*1024 + (q*256 + tt)
    int bn = flat >> 10, rem = flat & 1023;
    int q = rem >> 8, tt = rem & 255;
    int i = tt * 4 + q;                          // query index this slot holds
    int b = bn >> 4, n = bn & 15;
    float d = 0.f, s0 = 0.f, s1 = 0.f, s2 = 0.f, s3 = 0.f, s4 = 0.f, s5 = 0.f;
    #pragma unroll
    for (int jc = 0; jc < 16; ++jc) {
        uint4 u = P[(((size_t)(jc * 64 + bn)) << 10) + rem];   // lane-consecutive
        h2 x0 = ash2(u.y), x1 = ash2(u.z), x2 = ash2(u.w);
        d  += __uint_as_float(u.x);
        s0 += (float)x0.x; s1 += (float)x0.y;
        s2 += (float)x1.x; s3 += (float)x1.y;
        s4 += (float)x2.x; s5 += (float)x2.y;
    }
    float inv = 1.0f / d;
    float* o = AV + ((size_t)(b * 1024 + i)) * 96 + n * 6;
    o[0] = s0 * inv; o[1] = s1 * inv; o[2] = s2 * inv;
    o[3] = s3 * inv; o[4] = s4 * inv; o[5] = s5 * inv;
}

// ---------------- kernel 4: Wo projection + residual + LayerNorm ----------------
// 512 blocks x 256 thr, 8 rows/block; Wo staged once per block as f16 pairs.
__global__ __launch_bounds__(256)
void k_out(const float* __restrict__ AV, const float* __restrict__ Wo,
           const float* __restrict__ bo, const float* __restrict__ x,
           const float* __restrict__ gamma, const float* __restrict__ beta,
           float* __restrict__ out) {
    __shared__ unsigned WoS[96 * 96];   // 36864 B
    __shared__ float avS[8 * 96];       // 3072 B
    int tid = threadIdx.x;
    int row0 = blockIdx.x * 8;
    for (int idx = tid; idx < 9216; idx += 256) {
        int c = idx / 96, pd = idx - c * 96;
        float2 w = *(const float2*)&Wo[c * 192 + pd * 2];
        WoS[idx] = packh2(w.x, w.y);
    }
    for (int idx = tid; idx < 768; idx += 256)
        avS[idx] = AV[(size_t)row0 * 96 + idx];
    __syncthreads();

    int lane = tid & 63, wv = tid >> 6;
    bool act = lane < 48;
    int d0 = lane * 4;
    #pragma unroll
    for (int rr = 0; rr < 2; ++rr) {
        int r = wv * 2 + rr, row = row0 + r;
        float ax = 0.f, ay = 0.f, az = 0.f, aw = 0.f;
        if (act) {
            float4 bq = *(const float4*)&bo[d0];
            float4 xq = *(const float4*)&x[(size_t)row * 192 + d0];
            ax = bq.x + xq.x; ay = bq.y + xq.y; az = bq.z + xq.z; aw = bq.w + xq.w;
            for (int c2 = 0; c2 < 96; ++c2) {
                float a = avS[r * 96 + c2];
                uint2 wp = *(uint2*)&WoS[c2 * 96 + lane * 2];
                h2 w0 = ash2(wp.x), w1 = ash2(wp.y);
                ax += a * (float)w0.x; ay += a * (float)w0.y;
                az += a * (float)w1.x; aw += a * (float)w1.y;
            }
        }
        float sum = act ? (ax + ay + az + aw) : 0.f;
        #pragma unroll
        for (int off = 32; off; off >>= 1) sum += __shfl_xor(sum, off, 64);
        float mu = sum * (1.0f / 192.0f);
        float dx = ax - mu, dy = ay - mu, dz = az - mu, dw = aw - mu;
        float vs = act ? (dx * dx + dy * dy + dz * dz + dw * dw) : 0.f;
        #pragma unroll
        for (int off = 32; off; off >>= 1) vs += __shfl_xor(vs, off, 64);
        float rstd = rsqrtf(vs * (1.0f / 192.0f) + 1e-9f);
        if (act) {
            float4 g = *(const float4*)&gamma[d0];
            float4 bb = *(const float4*)&beta[d0];
            float4 rv;
            rv.x = dx * rstd * g.x + bb.x;
            rv.y = dy * rstd * g.y + bb.y;
            rv.z = dz * rstd * g.z + bb.z;
            rv.w = dw * rstd * g.w + bb.w;
            *(float4*)&out[(size_t)row * 192 + d0] = rv;
        }
    }
}

// ---------------- launch ----------------
extern "C" void kernel_launch(void* const* d_in, const int* in_sizes, int n_in,
                              void* d_out, int out_size, void* d_ws, size_t ws_size,
                              hipStream_t stream) {
    const float* x        = (const float*)d_in[0];
    const float* mask0    = (const float*)d_in[1];
    const float* Wq       = (const float*)d_in[2];
    const float* Wk       = (const float*)d_in[3];
    const float* bk       = (const float*)d_in[4];
    const float* Wv       = (const float*)d_in[5];
    const float* bv       = (const float*)d_in[6];
    const float* Wo       = (const float*)d_in[7];
    const float* bo       = (const float*)d_in[8];
    const float* rwb      = (const float*)d_in[9];
    const float* rrb      = (const float*)d_in[10];
    const float* r_kernel = (const float*)d_in[11];
    const float* gamma    = (const float*)d_in[12];
    const float* beta     = (const float*)d_in[13];
    float* out = (float*)d_out;

    unsigned* QWt = (unsigned*)d_ws;                       // 196608 dwords
    unsigned* QRt = QWt + 196608;                          // 196608
    unsigned* Kpl = QRt + 196608;                          // 196608
    unsigned* Vpl = Kpl + 196608;                          // 196608
    uint4*    P   = (uint4*)(Vpl + 196608);                // 1048576 uint4 (16 MB)
    unsigned short* phiB = (unsigned short*)(P + 1048576); // 262144 ushorts
    unsigned* Whp = (unsigned*)(phiB + 262144);            // 27648 dwords
    float*    AV  = (float*)(Whp + 27648);                 // 393216 floats (1.5 MB)

    k_wpack<<<288, 96, 0, stream>>>(Wq, Wk, Wv, Whp);
    k_pre<<<1664, 256, 0, stream>>>(x, Whp, bk, bv, rwb, rrb, r_kernel,
                                    QWt, QRt, Kpl, Vpl, phiB);
    k_attn<<<dim3(16, 16, 4), 256, 0, stream>>>(QWt, QRt, Kpl, Vpl, mask0, phiB, P);
    k_comb<<<256, 256, 0, stream>>>(P, AV);
    k_out<<<512, 256, 0, stream>>>(AV, Wo, bo, x, gamma, beta, out);
}